// Round 1
// baseline (728.489 us; speedup 1.0000x reference)
//
#include <hip/hip_runtime.h>
#include <hip/hip_bf16.h>
#include <math.h>

#define TOKS 4096

__device__ __forceinline__ float dot4(float4 a, float4 b) {
    return a.x*b.x + a.y*b.y + a.z*b.z + a.w*b.w;
}

// ---------------------------------------------------------------------------
// Kernel 1: routing. Each wave handles 4 tokens; x rows held in registers.
// Computes 84 decision dots + 12 gate dots per token, then sigmoid/leaf-prob/
// gate-softmax postprocessing. Output: coeff[4096][96] (= weight_t * leafprob).
// ---------------------------------------------------------------------------
__global__ __launch_bounds__(256) void routing_kernel(
    const float* __restrict__ x,        // [4096][1024]
    const float* __restrict__ dw,       // [84][1024]
    const float* __restrict__ db,       // [84]
    const float* __restrict__ ntl,      // [84]
    const float* __restrict__ gate_w,   // [1024][12]
    const float* __restrict__ gate_b,   // [12]
    float* __restrict__ coeff)          // [4096][96]
{
    __shared__ float raw[16][96];
    const int tid  = threadIdx.x;
    const int wave = tid >> 6, lane = tid & 63;
    const int tok0 = blockIdx.x * 16 + wave * 4;

    // x rows in registers: lane owns d = ii*256 + lane*4 + j (ii<4, j<4)
    float xr[4][16];
    #pragma unroll
    for (int tkn = 0; tkn < 4; ++tkn)
        #pragma unroll
        for (int ii = 0; ii < 4; ++ii)
            *(float4*)&xr[tkn][ii*4] =
                *(const float4*)&x[(size_t)(tok0 + tkn)*1024 + ii*256 + lane*4];

    // 84 decision dots
    #pragma unroll 2
    for (int o = 0; o < 84; ++o) {
        float a0=0.f,a1=0.f,a2=0.f,a3=0.f;
        #pragma unroll
        for (int ii = 0; ii < 4; ++ii) {
            float4 w4 = *(const float4*)&dw[o*1024 + ii*256 + lane*4];
            a0 += w4.x*xr[0][ii*4+0] + w4.y*xr[0][ii*4+1] + w4.z*xr[0][ii*4+2] + w4.w*xr[0][ii*4+3];
            a1 += w4.x*xr[1][ii*4+0] + w4.y*xr[1][ii*4+1] + w4.z*xr[1][ii*4+2] + w4.w*xr[1][ii*4+3];
            a2 += w4.x*xr[2][ii*4+0] + w4.y*xr[2][ii*4+1] + w4.z*xr[2][ii*4+2] + w4.w*xr[2][ii*4+3];
            a3 += w4.x*xr[3][ii*4+0] + w4.y*xr[3][ii*4+1] + w4.z*xr[3][ii*4+2] + w4.w*xr[3][ii*4+3];
        }
        for (int off = 32; off; off >>= 1) {
            a0 += __shfl_down(a0, off); a1 += __shfl_down(a1, off);
            a2 += __shfl_down(a2, off); a3 += __shfl_down(a3, off);
        }
        if (lane == 0) {
            raw[wave*4+0][o] = a0; raw[wave*4+1][o] = a1;
            raw[wave*4+2][o] = a2; raw[wave*4+3][o] = a3;
        }
    }
    // 12 gate dots (gate_w is [D][T], column access, L2-resident)
    for (int t = 0; t < 12; ++t) {
        float a0=0.f,a1=0.f,a2=0.f,a3=0.f;
        #pragma unroll
        for (int ii = 0; ii < 4; ++ii) {
            #pragma unroll
            for (int j = 0; j < 4; ++j) {
                float w = gate_w[(ii*256 + lane*4 + j)*12 + t];
                a0 += w * xr[0][ii*4+j]; a1 += w * xr[1][ii*4+j];
                a2 += w * xr[2][ii*4+j]; a3 += w * xr[3][ii*4+j];
            }
        }
        for (int off = 32; off; off >>= 1) {
            a0 += __shfl_down(a0, off); a1 += __shfl_down(a1, off);
            a2 += __shfl_down(a2, off); a3 += __shfl_down(a3, off);
        }
        if (lane == 0) {
            raw[wave*4+0][84+t] = a0; raw[wave*4+1][84+t] = a1;
            raw[wave*4+2][84+t] = a2; raw[wave*4+3][84+t] = a3;
        }
    }
    __syncthreads();

    // postprocess: 16 tokens x 12 trees = 192 threads
    if (tid < 192) {
        const int lt = tid / 12, t = tid - lt*12;
        float dec[7];
        #pragma unroll
        for (int n = 0; n < 7; ++n) {
            float tempv = log1pf(expf(ntl[t*7+n] + 0.5413f));   // TEMPERATURE=1
            float v = (raw[lt][t*7+n] + db[t*7+n]) / tempv;
            dec[n] = 1.f / (1.f + expf(-v));
        }
        float g[12], gmax = -3e38f;
        #pragma unroll
        for (int tt = 0; tt < 12; ++tt) {
            g[tt] = raw[lt][84+tt] + gate_b[tt];
            gmax = fmaxf(gmax, g[tt]);
        }
        float gsum = 0.f;
        #pragma unroll
        for (int tt = 0; tt < 12; ++tt) gsum += expf(g[tt]-gmax);
        const float wgt = expf(g[t]-gmax) / gsum;
        const int tok = blockIdx.x*16 + lt;
        #pragma unroll
        for (int l = 0; l < 8; ++l) {
            float p = wgt; int node = 0;
            #pragma unroll
            for (int dpt = 0; dpt < 3; ++dpt) {
                int bit = (l >> (2-dpt)) & 1;
                float r = dec[node];
                p *= bit ? (1.f - r) : r;
                node = 2*node + 1 + bit;
            }
            coeff[tok*96 + t*8 + l] = p;
        }
    }
}

// ---------------------------------------------------------------------------
// Kernel 2: qkv[h][tok][d] = coeff[tok][:] @ leaf[h][:][d].  M=4096,K=96,N=3072
// Tile 64x128, 256 threads, 8x4 micro-tile.
// ---------------------------------------------------------------------------
__global__ __launch_bounds__(256) void mix_kernel(
    const float* __restrict__ coeff,   // [4096][96]
    const float* __restrict__ leaf,    // [3][96][1024]
    float* __restrict__ qkv)           // [3][4096][1024]
{
    const int bn = blockIdx.x;             // 0..23 (col tile of 128 over 3072)
    const int bm = blockIdx.y;             // 0..63 (row tile of 64)
    const int col0 = bn * 128;
    const int h  = col0 >> 10;
    const int d0 = col0 & 1023;
    __shared__ float csT[96][68];          // coeff transposed, padded
    __shared__ float wst[96][128];
    const int tid = threadIdx.x;
    for (int i = tid; i < 64*96; i += 256) {
        int r = i / 96, k = i - r*96;
        csT[k][r] = coeff[(bm*64 + r)*96 + k];
    }
    for (int i = tid; i < 96*128; i += 256) {
        int k = i >> 7, c = i & 127;
        wst[k][c] = leaf[h*98304 + k*1024 + d0 + c];
    }
    __syncthreads();
    const int tx = tid & 31, ty = tid >> 5;
    float acc[8][4] = {};
    #pragma unroll 4
    for (int k = 0; k < 96; ++k) {
        float4 w4 = *(const float4*)&wst[k][tx*4];
        float4 c0 = *(const float4*)&csT[k][ty*8];
        float4 c1 = *(const float4*)&csT[k][ty*8+4];
        float cr[8] = {c0.x,c0.y,c0.z,c0.w,c1.x,c1.y,c1.z,c1.w};
        #pragma unroll
        for (int i = 0; i < 8; ++i) {
            acc[i][0] += cr[i]*w4.x; acc[i][1] += cr[i]*w4.y;
            acc[i][2] += cr[i]*w4.z; acc[i][3] += cr[i]*w4.w;
        }
    }
    #pragma unroll
    for (int i = 0; i < 8; ++i) {
        int row = bm*64 + ty*8 + i;
        float4 v = make_float4(acc[i][0],acc[i][1],acc[i][2],acc[i][3]);
        *(float4*)&qkv[(size_t)h*TOKS*1024 + (size_t)row*1024 + d0 + tx*4] = v;
    }
}

// ---------------------------------------------------------------------------
// Kernel 3: causal flash attention, f32 vector. Block = (qblock 64, head, batch).
// 256 threads: ty=tid/16 -> 4 q rows, tx=tid%16 -> 4 key cols (scores) and
// 4 dh cols (output). Online softmax with stats replicated across the 16
// lanes sharing a q row.
// ---------------------------------------------------------------------------
__global__ __launch_bounds__(256) void attn_kernel(
    const float* __restrict__ qkv,   // [3][4096][1024]
    float* __restrict__ ctx)         // [4096][1024]  (d = h*64+dh)
{
    const int qb = blockIdx.x, h = blockIdx.y, b = blockIdx.z;
    const int tid = threadIdx.x;
    const int tx = tid & 15, ty = tid >> 4;
    __shared__ float qs[64][68], ks[64][68], vs[64][68], pT[64][68];
    const size_t plane = (size_t)TOKS*1024;
    const int tokq0 = b*1024 + qb*64;

    for (int i = tid; i < 1024; i += 256) {
        int r = i >> 4, c4 = i & 15;
        *(float4*)&qs[r][c4*4] =
            *(const float4*)&qkv[(size_t)(tokq0+r)*1024 + h*64 + c4*4];
    }

    float o[4][4] = {};
    float m[4] = {-3e38f,-3e38f,-3e38f,-3e38f};
    float l[4] = {0.f,0.f,0.f,0.f};

    for (int kt = 0; kt <= qb; ++kt) {
        __syncthreads();   // previous PV (readers of vs/pT) done
        const int tokk0 = b*1024 + kt*64;
        for (int i = tid; i < 1024; i += 256) {
            int r = i >> 4, c4 = i & 15;
            *(float4*)&ks[r][c4*4] =
                *(const float4*)&qkv[plane   + (size_t)(tokk0+r)*1024 + h*64 + c4*4];
            *(float4*)&vs[r][c4*4] =
                *(const float4*)&qkv[2*plane + (size_t)(tokk0+r)*1024 + h*64 + c4*4];
        }
        __syncthreads();

        float sc[4][4] = {};
        #pragma unroll
        for (int dd = 0; dd < 16; ++dd) {
            float4 qv[4], kv[4];
            #pragma unroll
            for (int i = 0; i < 4; ++i) qv[i] = *(const float4*)&qs[ty*4+i][dd*4];
            #pragma unroll
            for (int j = 0; j < 4; ++j) kv[j] = *(const float4*)&ks[tx*4+j][dd*4];
            #pragma unroll
            for (int i = 0; i < 4; ++i)
                #pragma unroll
                for (int j = 0; j < 4; ++j)
                    sc[i][j] += dot4(qv[i], kv[j]);
        }
        const bool diag = (kt == qb);
        #pragma unroll
        for (int i = 0; i < 4; ++i)
            #pragma unroll
            for (int j = 0; j < 4; ++j) {
                float s = sc[i][j] * 0.125f;
                if (diag && (tx*4+j > ty*4+i)) s = -1e9f;
                sc[i][j] = s;
            }
        #pragma unroll
        for (int i = 0; i < 4; ++i) {
            float rm = fmaxf(fmaxf(sc[i][0],sc[i][1]), fmaxf(sc[i][2],sc[i][3]));
            for (int off = 1; off < 16; off <<= 1) rm = fmaxf(rm, __shfl_xor(rm, off));
            float mnew = fmaxf(m[i], rm);
            float corr = __expf(m[i] - mnew);
            float ps = 0.f;
            #pragma unroll
            for (int j = 0; j < 4; ++j) {
                float p = __expf(sc[i][j] - mnew);
                sc[i][j] = p; ps += p;
            }
            for (int off = 1; off < 16; off <<= 1) ps += __shfl_xor(ps, off);
            l[i] = l[i]*corr + ps;
            #pragma unroll
            for (int j = 0; j < 4; ++j) o[i][j] *= corr;
            m[i] = mnew;
        }
        #pragma unroll
        for (int i = 0; i < 4; ++i)
            #pragma unroll
            for (int j = 0; j < 4; ++j)
                pT[tx*4+j][ty*4+i] = sc[i][j];
        __syncthreads();
        #pragma unroll 8
        for (int k0 = 0; k0 < 64; ++k0) {
            float4 pv = *(const float4*)&pT[k0][ty*4];
            float4 vv = *(const float4*)&vs[k0][tx*4];
            o[0][0] += pv.x*vv.x; o[0][1] += pv.x*vv.y; o[0][2] += pv.x*vv.z; o[0][3] += pv.x*vv.w;
            o[1][0] += pv.y*vv.x; o[1][1] += pv.y*vv.y; o[1][2] += pv.y*vv.z; o[1][3] += pv.y*vv.w;
            o[2][0] += pv.z*vv.x; o[2][1] += pv.z*vv.y; o[2][2] += pv.z*vv.z; o[2][3] += pv.z*vv.w;
            o[3][0] += pv.w*vv.x; o[3][1] += pv.w*vv.y; o[3][2] += pv.w*vv.z; o[3][3] += pv.w*vv.w;
        }
    }
    #pragma unroll
    for (int i = 0; i < 4; ++i) {
        float inv = 1.f / l[i];
        float4 v = make_float4(o[i][0]*inv, o[i][1]*inv, o[i][2]*inv, o[i][3]*inv);
        *(float4*)&ctx[(size_t)(tokq0 + ty*4+i)*1024 + h*64 + tx*4] = v;
    }
}

// ---------------------------------------------------------------------------
// Kernel 4: out = ctx @ out_w + out_b.  M=4096,K=1024,N=1024.
// Tile 128x64, BK=32, 256 threads, 8x4 micro-tile.
// ---------------------------------------------------------------------------
__global__ __launch_bounds__(256) void proj_kernel(
    const float* __restrict__ A,     // ctx [4096][1024]
    const float* __restrict__ Bw,    // out_w [1024][1024]
    const float* __restrict__ bias,  // [1024]
    float* __restrict__ out)         // [4096][1024]
{
    const int bn = blockIdx.x;   // 16 col tiles of 64
    const int bm = blockIdx.y;   // 32 row tiles of 128
    __shared__ float AsT[32][132];
    __shared__ float Bs[32][68];
    const int tid = threadIdx.x;
    const int tx = tid & 15, ty = tid >> 4;
    float acc[8][4] = {};
    for (int kb = 0; kb < 32; ++kb) {
        __syncthreads();
        for (int i = tid; i < 128*32; i += 256) {
            int r = i >> 5, c = i & 31;
            AsT[c][r] = A[(size_t)(bm*128 + r)*1024 + kb*32 + c];
        }
        for (int i = tid; i < 32*64; i += 256) {
            int r = i >> 6, c = i & 63;
            Bs[r][c] = Bw[(size_t)(kb*32 + r)*1024 + bn*64 + c];
        }
        __syncthreads();
        #pragma unroll 8
        for (int kk = 0; kk < 32; ++kk) {
            float4 a0 = *(const float4*)&AsT[kk][ty*8];
            float4 a1 = *(const float4*)&AsT[kk][ty*8+4];
            float4 b0 = *(const float4*)&Bs[kk][tx*4];
            float ar[8] = {a0.x,a0.y,a0.z,a0.w,a1.x,a1.y,a1.z,a1.w};
            #pragma unroll
            for (int i = 0; i < 8; ++i) {
                acc[i][0] += ar[i]*b0.x; acc[i][1] += ar[i]*b0.y;
                acc[i][2] += ar[i]*b0.z; acc[i][3] += ar[i]*b0.w;
            }
        }
    }
    #pragma unroll
    for (int i = 0; i < 8; ++i) {
        int row = bm*128 + ty*8 + i;
        int col = bn*64 + tx*4;
        float4 bb = *(const float4*)&bias[col];
        float4 v = make_float4(acc[i][0]+bb.x, acc[i][1]+bb.y,
                               acc[i][2]+bb.z, acc[i][3]+bb.w);
        *(float4*)&out[(size_t)row*1024 + col] = v;
    }
}

// ---------------------------------------------------------------------------
extern "C" void kernel_launch(void* const* d_in, const int* in_sizes, int n_in,
                              void* d_out, int out_size, void* d_ws, size_t ws_size,
                              hipStream_t stream) {
    (void)in_sizes; (void)n_in; (void)out_size; (void)ws_size;
    const float* x      = (const float*)d_in[0];
    const float* dw     = (const float*)d_in[1];
    const float* db     = (const float*)d_in[2];
    const float* ntl    = (const float*)d_in[3];
    const float* gate_w = (const float*)d_in[4];
    const float* gate_b = (const float*)d_in[5];
    const float* leaf   = (const float*)d_in[6];
    const float* out_w  = (const float*)d_in[7];
    const float* out_b  = (const float*)d_in[8];
    float* out = (float*)d_out;

    // workspace layout (bytes): coeff @0 (1.5MB), qkv @2MB (48MB), ctx @50MB (16.8MB)
    float* coeff = (float*)d_ws;
    float* qkv   = (float*)((char*)d_ws + (size_t)(2u  << 20));
    float* ctx   = (float*)((char*)d_ws + (size_t)(50u << 20));

    hipLaunchKernelGGL(routing_kernel, dim3(256),      dim3(256), 0, stream,
                       x, dw, db, ntl, gate_w, gate_b, coeff);
    hipLaunchKernelGGL(mix_kernel,     dim3(24, 64),   dim3(256), 0, stream,
                       coeff, leaf, qkv);
    hipLaunchKernelGGL(attn_kernel,    dim3(16, 16, 4), dim3(256), 0, stream,
                       qkv, ctx);
    hipLaunchKernelGGL(proj_kernel,    dim3(16, 32),   dim3(256), 0, stream,
                       ctx, out_w, out_b, out);
}

// Round 3
// 362.476 us; speedup vs baseline: 2.0098x; 2.0098x over previous
//
#include <hip/hip_runtime.h>
#include <hip/hip_bf16.h>
#include <math.h>

#define TOKS 4096

typedef __attribute__((ext_vector_type(4))) float    f32x4;
typedef __attribute__((ext_vector_type(8))) short    short8;
typedef __attribute__((ext_vector_type(4))) unsigned short ushort4v;
typedef unsigned short ushort;

__device__ __forceinline__ ushort f2b(float f) {   // f32 -> bf16 bits, RNE
    unsigned int b = __float_as_uint(f);
    b += 0x7fff + ((b >> 16) & 1);
    return (ushort)(b >> 16);
}

// ---------------------------------------------------------------------------
// Kernel 1: routing (f32). coeff[4096][96] = gate_weight * leaf_prob
// ---------------------------------------------------------------------------
__global__ __launch_bounds__(256) void routing_kernel(
    const float* __restrict__ x,        // [4096][1024]
    const float* __restrict__ dw,       // [84][1024]
    const float* __restrict__ db,       // [84]
    const float* __restrict__ ntl,      // [84]
    const float* __restrict__ gate_w,   // [1024][12]
    const float* __restrict__ gate_b,   // [12]
    float* __restrict__ coeff)          // [4096][96]
{
    __shared__ float raw[16][96];
    const int tid  = threadIdx.x;
    const int wave = tid >> 6, lane = tid & 63;
    const int tok0 = blockIdx.x * 16 + wave * 4;

    float xr[4][16];
    #pragma unroll
    for (int tkn = 0; tkn < 4; ++tkn)
        #pragma unroll
        for (int ii = 0; ii < 4; ++ii)
            *(float4*)&xr[tkn][ii*4] =
                *(const float4*)&x[(size_t)(tok0 + tkn)*1024 + ii*256 + lane*4];

    #pragma unroll 2
    for (int o = 0; o < 84; ++o) {
        float a0=0.f,a1=0.f,a2=0.f,a3=0.f;
        #pragma unroll
        for (int ii = 0; ii < 4; ++ii) {
            float4 w4 = *(const float4*)&dw[o*1024 + ii*256 + lane*4];
            a0 += w4.x*xr[0][ii*4+0] + w4.y*xr[0][ii*4+1] + w4.z*xr[0][ii*4+2] + w4.w*xr[0][ii*4+3];
            a1 += w4.x*xr[1][ii*4+0] + w4.y*xr[1][ii*4+1] + w4.z*xr[1][ii*4+2] + w4.w*xr[1][ii*4+3];
            a2 += w4.x*xr[2][ii*4+0] + w4.y*xr[2][ii*4+1] + w4.z*xr[2][ii*4+2] + w4.w*xr[2][ii*4+3];
            a3 += w4.x*xr[3][ii*4+0] + w4.y*xr[3][ii*4+1] + w4.z*xr[3][ii*4+2] + w4.w*xr[3][ii*4+3];
        }
        for (int off = 32; off; off >>= 1) {
            a0 += __shfl_down(a0, off); a1 += __shfl_down(a1, off);
            a2 += __shfl_down(a2, off); a3 += __shfl_down(a3, off);
        }
        if (lane == 0) {
            raw[wave*4+0][o] = a0; raw[wave*4+1][o] = a1;
            raw[wave*4+2][o] = a2; raw[wave*4+3][o] = a3;
        }
    }
    for (int t = 0; t < 12; ++t) {
        float a0=0.f,a1=0.f,a2=0.f,a3=0.f;
        #pragma unroll
        for (int ii = 0; ii < 4; ++ii) {
            #pragma unroll
            for (int j = 0; j < 4; ++j) {
                float w = gate_w[(ii*256 + lane*4 + j)*12 + t];
                a0 += w * xr[0][ii*4+j]; a1 += w * xr[1][ii*4+j];
                a2 += w * xr[2][ii*4+j]; a3 += w * xr[3][ii*4+j];
            }
        }
        for (int off = 32; off; off >>= 1) {
            a0 += __shfl_down(a0, off); a1 += __shfl_down(a1, off);
            a2 += __shfl_down(a2, off); a3 += __shfl_down(a3, off);
        }
        if (lane == 0) {
            raw[wave*4+0][84+t] = a0; raw[wave*4+1][84+t] = a1;
            raw[wave*4+2][84+t] = a2; raw[wave*4+3][84+t] = a3;
        }
    }
    __syncthreads();

    if (tid < 192) {
        const int lt = tid / 12, t = tid - lt*12;
        float dec[7];
        #pragma unroll
        for (int n = 0; n < 7; ++n) {
            float tempv = log1pf(expf(ntl[t*7+n] + 0.5413f));
            float v = (raw[lt][t*7+n] + db[t*7+n]) / tempv;
            dec[n] = 1.f / (1.f + expf(-v));
        }
        float g[12], gmax = -3e38f;
        #pragma unroll
        for (int tt = 0; tt < 12; ++tt) {
            g[tt] = raw[lt][84+tt] + gate_b[tt];
            gmax = fmaxf(gmax, g[tt]);
        }
        float gsum = 0.f;
        #pragma unroll
        for (int tt = 0; tt < 12; ++tt) gsum += expf(g[tt]-gmax);
        const float wgt = expf(g[t]-gmax) / gsum;
        const int tok = blockIdx.x*16 + lt;
        #pragma unroll
        for (int l = 0; l < 8; ++l) {
            float p = wgt; int node = 0;
            #pragma unroll
            for (int dpt = 0; dpt < 3; ++dpt) {
                int bit = (l >> (2-dpt)) & 1;
                float r = dec[node];
                p *= bit ? (1.f - r) : r;
                node = 2*node + 1 + bit;
            }
            coeff[tok*96 + t*8 + l] = p;
        }
    }
}

// ---------------------------------------------------------------------------
// Kernel 2: qkv mix -> bf16 planes [3][4096][1024]
// ---------------------------------------------------------------------------
__global__ __launch_bounds__(256) void mix_kernel(
    const float* __restrict__ coeff,   // [4096][96]
    const float* __restrict__ leaf,    // [3][96][1024]
    ushort* __restrict__ qkvb)         // [3][4096][1024] bf16
{
    const int bn = blockIdx.x;
    const int bm = blockIdx.y;
    const int col0 = bn * 128;
    const int h  = col0 >> 10;
    const int d0 = col0 & 1023;
    __shared__ float csT[96][68];
    __shared__ float wst[96][128];
    const int tid = threadIdx.x;
    for (int i = tid; i < 64*96; i += 256) {
        int r = i / 96, k = i - r*96;
        csT[k][r] = coeff[(bm*64 + r)*96 + k];
    }
    for (int i = tid; i < 96*128; i += 256) {
        int k = i >> 7, c = i & 127;
        wst[k][c] = leaf[h*98304 + k*1024 + d0 + c];
    }
    __syncthreads();
    const int tx = tid & 31, ty = tid >> 5;
    float acc[8][4] = {};
    #pragma unroll 4
    for (int k = 0; k < 96; ++k) {
        float4 w4 = *(const float4*)&wst[k][tx*4];
        float4 c0 = *(const float4*)&csT[k][ty*8];
        float4 c1 = *(const float4*)&csT[k][ty*8+4];
        float cr[8] = {c0.x,c0.y,c0.z,c0.w,c1.x,c1.y,c1.z,c1.w};
        #pragma unroll
        for (int i = 0; i < 8; ++i) {
            acc[i][0] += cr[i]*w4.x; acc[i][1] += cr[i]*w4.y;
            acc[i][2] += cr[i]*w4.z; acc[i][3] += cr[i]*w4.w;
        }
    }
    const size_t plane = (size_t)TOKS*1024;
    #pragma unroll
    for (int i = 0; i < 8; ++i) {
        int row = bm*64 + ty*8 + i;
        ushort4v u;
        u[0] = f2b(acc[i][0]); u[1] = f2b(acc[i][1]);
        u[2] = f2b(acc[i][2]); u[3] = f2b(acc[i][3]);
        *(ushort4v*)&qkvb[(size_t)h*plane + (size_t)row*1024 + d0 + tx*4] = u;
    }
}

// ---------------------------------------------------------------------------
// Kernel 3a: V plane -> vT[bh][dh=64][s=1024] bf16 (per (b,h) transpose)
// ---------------------------------------------------------------------------
__global__ __launch_bounds__(256) void vtrans_kernel(
    const ushort* __restrict__ vplane,  // qkvb plane 2: [4096][1024]
    ushort* __restrict__ vT)            // [64][64][1024]
{
    __shared__ ushort t[64][72];
    const int st = blockIdx.x, bh = blockIdx.y;
    const int b = bh >> 4, h = bh & 15;
    const int tid = threadIdx.x;
    const int r = tid >> 3, c8 = (tid & 7) * 8;
    #pragma unroll
    for (int rr = r; rr < 64; rr += 32)
        *(short8*)&t[rr][c8] =
            *(const short8*)&vplane[(size_t)(b*1024 + st*64 + rr)*1024 + h*64 + c8];
    __syncthreads();
    #pragma unroll
    for (int dd = r; dd < 64; dd += 32) {
        short8 o;
        #pragma unroll
        for (int j = 0; j < 8; ++j) o[j] = (short)t[c8+j][dd];
        *(short8*)&vT[((size_t)bh*64 + dd)*1024 + st*64 + c8] = o;
    }
}

// ---------------------------------------------------------------------------
// Kernel 3b: out_w [1024][1024] f32 -> wT [n][k] bf16 (transpose + convert)
// ---------------------------------------------------------------------------
__global__ __launch_bounds__(256) void wtrans_kernel(
    const float* __restrict__ w, ushort* __restrict__ wT)
{
    __shared__ float t[64][65];
    const int n0 = blockIdx.x * 64, k0 = blockIdx.y * 64;
    const int tid = threadIdx.x;
    const int r = tid >> 2, c16 = (tid & 3) * 16;
    #pragma unroll
    for (int j = 0; j < 16; j += 4)
        *(float4*)&t[r][c16+j] = *(const float4*)&w[(size_t)(k0+r)*1024 + n0 + c16 + j];
    __syncthreads();
    short8 o0, o1;
    #pragma unroll
    for (int j = 0; j < 8; ++j) o0[j] = (short)f2b(t[c16+j][r]);
    #pragma unroll
    for (int j = 0; j < 8; ++j) o1[j] = (short)f2b(t[c16+8+j][r]);
    *(short8*)&wT[(size_t)(n0+r)*1024 + k0 + c16]     = o0;
    *(short8*)&wT[(size_t)(n0+r)*1024 + k0 + c16 + 8] = o1;
}

// ---------------------------------------------------------------------------
// Kernel 4: MFMA flash attention. 4 waves/block, 16 q rows/wave, KV tile 64.
// All operand fragments are contiguous 16B loads (L2-resident K and vT).
// pT padded to 26 ushorts: fragment-gather read banks = lg*8 + lq/2 -> all 32
// banks, 2 lanes/bank (free); the old 24-pad aliased all lg groups (4-way).
// ---------------------------------------------------------------------------
__global__ __launch_bounds__(256) void attn_kernel(
    const ushort* __restrict__ qk,    // [2][4096][1024] bf16 (Q,K planes)
    const ushort* __restrict__ vT,    // [64][64][1024] bf16
    ushort* __restrict__ ctxb)        // [4096][1024] bf16
{
    const int qb = blockIdx.x, bh = blockIdx.y;
    const int b = bh >> 4, h = bh & 15;
    const int tid = threadIdx.x;
    const int w = tid >> 6, lane = tid & 63;
    const int lq = lane & 15, lg = lane >> 4;
    __shared__ ushort pT[4][64][26];          // per-wave P^T staging

    const size_t plane = (size_t)TOKS*1024;
    const int tokq = b*1024 + qb*64 + w*16 + lq;
    short8 aq[2];
    aq[0] = *(const short8*)&qk[(size_t)tokq*1024 + h*64 + lg*8];
    aq[1] = *(const short8*)&qk[(size_t)tokq*1024 + h*64 + 32 + lg*8];

    f32x4 o[4];
    #pragma unroll
    for (int n = 0; n < 4; ++n) o[n] = (f32x4){0.f,0.f,0.f,0.f};
    float m[4] = {-3e38f,-3e38f,-3e38f,-3e38f};
    float l[4] = {0.f,0.f,0.f,0.f};

    const ushort* Kp  = qk + plane;
    const ushort* vTp = vT + (size_t)bh*64*1024;

    for (int kt = 0; kt <= qb; ++kt) {
        const int tk0 = b*1024 + kt*64;
        f32x4 s[4];
        #pragma unroll
        for (int n = 0; n < 4; ++n) s[n] = (f32x4){0.f,0.f,0.f,0.f};
        #pragma unroll
        for (int kk = 0; kk < 2; ++kk)
            #pragma unroll
            for (int n = 0; n < 4; ++n) {
                short8 bk = *(const short8*)&Kp[(size_t)(tk0 + n*16 + lq)*1024 + h*64 + kk*32 + lg*8];
                s[n] = __builtin_amdgcn_mfma_f32_16x16x32_bf16(aq[kk], bk, s[n], 0, 0, 0);
            }

        const bool diag = (kt == qb);
        if (diag) {
            #pragma unroll
            for (int n = 0; n < 4; ++n)
                #pragma unroll
                for (int r = 0; r < 4; ++r) {
                    float v = s[n][r] * 0.125f;
                    if (n*16 + lq > w*16 + lg*4 + r) v = -1e9f;
                    s[n][r] = v;
                }
        } else {
            #pragma unroll
            for (int n = 0; n < 4; ++n)
                #pragma unroll
                for (int r = 0; r < 4; ++r) s[n][r] *= 0.125f;
        }

        #pragma unroll
        for (int r = 0; r < 4; ++r) {
            float rm = fmaxf(fmaxf(s[0][r], s[1][r]), fmaxf(s[2][r], s[3][r]));
            rm = fmaxf(rm, __shfl_xor(rm, 1));
            rm = fmaxf(rm, __shfl_xor(rm, 2));
            rm = fmaxf(rm, __shfl_xor(rm, 4));
            rm = fmaxf(rm, __shfl_xor(rm, 8));
            float mnew = fmaxf(m[r], rm);
            float corr = __expf(m[r] - mnew);
            float ps = 0.f;
            #pragma unroll
            for (int n = 0; n < 4; ++n) {
                float p = __expf(s[n][r] - mnew);
                s[n][r] = p; ps += p;
            }
            ps += __shfl_xor(ps, 1);
            ps += __shfl_xor(ps, 2);
            ps += __shfl_xor(ps, 4);
            ps += __shfl_xor(ps, 8);
            l[r] = l[r]*corr + ps;
            m[r] = mnew;
            o[0][r] *= corr; o[1][r] *= corr; o[2][r] *= corr; o[3][r] *= corr;
        }

        // P (bf16) -> per-wave LDS transpose buffer: pT[t][q]
        #pragma unroll
        for (int n = 0; n < 4; ++n) {
            unsigned int lo = (unsigned int)f2b(s[n][0]) | ((unsigned int)f2b(s[n][1]) << 16);
            unsigned int hi = (unsigned int)f2b(s[n][2]) | ((unsigned int)f2b(s[n][3]) << 16);
            unsigned int* dst = (unsigned int*)&pT[w][n*16 + lq][lg*4];
            dst[0] = lo; dst[1] = hi;
        }
        __syncthreads();

        short8 pa[2];
        #pragma unroll
        for (int kk = 0; kk < 2; ++kk)
            #pragma unroll
            for (int j = 0; j < 8; ++j)
                pa[kk][j] = (short)pT[w][kk*32 + lg*8 + j][lq];

        #pragma unroll
        for (int kk = 0; kk < 2; ++kk)
            #pragma unroll
            for (int n = 0; n < 4; ++n) {
                short8 bv = *(const short8*)&vTp[(size_t)(n*16 + lq)*1024 + kt*64 + kk*32 + lg*8];
                o[n] = __builtin_amdgcn_mfma_f32_16x16x32_bf16(pa[kk], bv, o[n], 0, 0, 0);
            }
    }

    #pragma unroll
    for (int r = 0; r < 4; ++r) {
        float inv = 1.f / l[r];
        int row = b*1024 + qb*64 + w*16 + lg*4 + r;
        #pragma unroll
        for (int n = 0; n < 4; ++n)
            ctxb[(size_t)row*1024 + h*64 + n*16 + lq] = f2b(o[n][r] * inv);
    }
}

// ---------------------------------------------------------------------------
// Kernel 5: out = ctx(bf16) @ wT(bf16)^T + bias, MFMA. 128x128 block tile,
// 4 waves (2x2), each wave 64x64 (4x4 fragments). Operands direct from L2.
// ---------------------------------------------------------------------------
__global__ __launch_bounds__(256) void proj_kernel(
    const ushort* __restrict__ A,     // ctx bf16 [4096][1024]
    const ushort* __restrict__ Bt,    // wT bf16 [1024(n)][1024(k)]
    const float* __restrict__ bias,   // [1024]
    float* __restrict__ out)          // [4096][1024]
{
    const int bn = blockIdx.x, bm = blockIdx.y;
    const int tid = threadIdx.x, w = tid >> 6, lane = tid & 63;
    const int wm = w >> 1, wn = w & 1;
    const int lq = lane & 15, lg = lane >> 4;
    const int row0 = bm*128 + wm*64;
    const int col0 = bn*128 + wn*64;

    f32x4 acc[4][4];
    #pragma unroll
    for (int i = 0; i < 4; ++i)
        #pragma unroll
        for (int j = 0; j < 4; ++j) acc[i][j] = (f32x4){0.f,0.f,0.f,0.f};

    for (int k0 = 0; k0 < 1024; k0 += 32) {
        short8 a[4], bfr[4];
        #pragma unroll
        for (int i = 0; i < 4; ++i)
            a[i] = *(const short8*)&A[(size_t)(row0 + i*16 + lq)*1024 + k0 + lg*8];
        #pragma unroll
        for (int j = 0; j < 4; ++j)
            bfr[j] = *(const short8*)&Bt[(size_t)(col0 + j*16 + lq)*1024 + k0 + lg*8];
        #pragma unroll
        for (int i = 0; i < 4; ++i)
            #pragma unroll
            for (int j = 0; j < 4; ++j)
                acc[i][j] = __builtin_amdgcn_mfma_f32_16x16x32_bf16(a[i], bfr[j], acc[i][j], 0, 0, 0);
    }

    #pragma unroll
    for (int i = 0; i < 4; ++i)
        #pragma unroll
        for (int j = 0; j < 4; ++j) {
            int col = col0 + j*16 + lq;
            float bb = bias[col];
            #pragma unroll
            for (int r = 0; r < 4; ++r)
                out[(size_t)(row0 + i*16 + lg*4 + r)*1024 + col] = acc[i][j][r] + bb;
        }
}

// ---------------------------------------------------------------------------
extern "C" void kernel_launch(void* const* d_in, const int* in_sizes, int n_in,
                              void* d_out, int out_size, void* d_ws, size_t ws_size,
                              hipStream_t stream) {
    (void)in_sizes; (void)n_in; (void)out_size; (void)ws_size;
    const float* x      = (const float*)d_in[0];
    const float* dw     = (const float*)d_in[1];
    const float* db     = (const float*)d_in[2];
    const float* ntl    = (const float*)d_in[3];
    const float* gate_w = (const float*)d_in[4];
    const float* gate_b = (const float*)d_in[5];
    const float* leaf   = (const float*)d_in[6];
    const float* out_w  = (const float*)d_in[7];
    const float* out_b  = (const float*)d_in[8];
    float* out = (float*)d_out;

    // ws layout (bytes): coeff@0 (1.5MB) | qkvb@2MB (24MB bf16) | vT@28MB (8MB)
    //                    ctxb@40MB (8MB) | wT@52MB (2MB)
    float*  coeff = (float*)d_ws;
    ushort* qkvb  = (ushort*)((char*)d_ws + ((size_t)2u  << 20));
    ushort* vT    = (ushort*)((char*)d_ws + ((size_t)28u << 20));
    ushort* ctxb  = (ushort*)((char*)d_ws + ((size_t)40u << 20));
    ushort* wT    = (ushort*)((char*)d_ws + ((size_t)52u << 20));

    hipLaunchKernelGGL(routing_kernel, dim3(256),       dim3(256), 0, stream,
                       x, dw, db, ntl, gate_w, gate_b, coeff);
    hipLaunchKernelGGL(wtrans_kernel,  dim3(16, 16),    dim3(256), 0, stream,
                       out_w, wT);
    hipLaunchKernelGGL(mix_kernel,     dim3(24, 64),    dim3(256), 0, stream,
                       coeff, leaf, qkvb);
    hipLaunchKernelGGL(vtrans_kernel,  dim3(16, 64),    dim3(256), 0, stream,
                       qkvb + (size_t)2*TOKS*1024, vT);
    hipLaunchKernelGGL(attn_kernel,    dim3(16, 64),    dim3(256), 0, stream,
                       qkvb, vT, ctxb);
    hipLaunchKernelGGL(proj_kernel,    dim3(8, 32),     dim3(256), 0, stream,
                       ctxb, wT, out_b, out);
}

// Round 7
// 295.612 us; speedup vs baseline: 2.4643x; 1.2262x over previous
//
#include <hip/hip_runtime.h>
#include <hip/hip_bf16.h>
#include <math.h>

#define TOKS 4096

typedef __attribute__((ext_vector_type(4))) float    f32x4;
typedef __attribute__((ext_vector_type(8))) short    short8;
typedef __attribute__((ext_vector_type(4))) unsigned short ushort4v;
typedef unsigned short ushort;

__device__ __forceinline__ ushort f2b(float f) {   // f32 -> bf16 bits, RNE
    unsigned int b = __float_as_uint(f);
    b += 0x7fff + ((b >> 16) & 1);
    return (ushort)(b >> 16);
}

// ---------------------------------------------------------------------------
// Kernel 1: routing (f32 math). coeffb[4096][96] bf16 = gate_weight*leaf_prob
// ---------------------------------------------------------------------------
__global__ __launch_bounds__(256) void routing_kernel(
    const float* __restrict__ x,        // [4096][1024]
    const float* __restrict__ dw,       // [84][1024]
    const float* __restrict__ db,       // [84]
    const float* __restrict__ ntl,      // [84]
    const float* __restrict__ gate_w,   // [1024][12]
    const float* __restrict__ gate_b,   // [12]
    ushort* __restrict__ coeffb)        // [4096][96] bf16
{
    __shared__ float raw[16][96];
    const int tid  = threadIdx.x;
    const int wave = tid >> 6, lane = tid & 63;
    const int tok0 = blockIdx.x * 16 + wave * 4;

    float xr[4][16];
    #pragma unroll
    for (int tkn = 0; tkn < 4; ++tkn)
        #pragma unroll
        for (int ii = 0; ii < 4; ++ii)
            *(float4*)&xr[tkn][ii*4] =
                *(const float4*)&x[(size_t)(tok0 + tkn)*1024 + ii*256 + lane*4];

    #pragma unroll 2
    for (int o = 0; o < 84; ++o) {
        float a0=0.f,a1=0.f,a2=0.f,a3=0.f;
        #pragma unroll
        for (int ii = 0; ii < 4; ++ii) {
            float4 w4 = *(const float4*)&dw[o*1024 + ii*256 + lane*4];
            a0 += w4.x*xr[0][ii*4+0] + w4.y*xr[0][ii*4+1] + w4.z*xr[0][ii*4+2] + w4.w*xr[0][ii*4+3];
            a1 += w4.x*xr[1][ii*4+0] + w4.y*xr[1][ii*4+1] + w4.z*xr[1][ii*4+2] + w4.w*xr[1][ii*4+3];
            a2 += w4.x*xr[2][ii*4+0] + w4.y*xr[2][ii*4+1] + w4.z*xr[2][ii*4+2] + w4.w*xr[2][ii*4+3];
            a3 += w4.x*xr[3][ii*4+0] + w4.y*xr[3][ii*4+1] + w4.z*xr[3][ii*4+2] + w4.w*xr[3][ii*4+3];
        }
        for (int off = 32; off; off >>= 1) {
            a0 += __shfl_down(a0, off); a1 += __shfl_down(a1, off);
            a2 += __shfl_down(a2, off); a3 += __shfl_down(a3, off);
        }
        if (lane == 0) {
            raw[wave*4+0][o] = a0; raw[wave*4+1][o] = a1;
            raw[wave*4+2][o] = a2; raw[wave*4+3][o] = a3;
        }
    }
    for (int t = 0; t < 12; ++t) {
        float a0=0.f,a1=0.f,a2=0.f,a3=0.f;
        #pragma unroll
        for (int ii = 0; ii < 4; ++ii) {
            #pragma unroll
            for (int j = 0; j < 4; ++j) {
                float w = gate_w[(ii*256 + lane*4 + j)*12 + t];
                a0 += w * xr[0][ii*4+j]; a1 += w * xr[1][ii*4+j];
                a2 += w * xr[2][ii*4+j]; a3 += w * xr[3][ii*4+j];
            }
        }
        for (int off = 32; off; off >>= 1) {
            a0 += __shfl_down(a0, off); a1 += __shfl_down(a1, off);
            a2 += __shfl_down(a2, off); a3 += __shfl_down(a3, off);
        }
        if (lane == 0) {
            raw[wave*4+0][84+t] = a0; raw[wave*4+1][84+t] = a1;
            raw[wave*4+2][84+t] = a2; raw[wave*4+3][84+t] = a3;
        }
    }
    __syncthreads();

    if (tid < 192) {
        const int lt = tid / 12, t = tid - lt*12;
        float dec[7];
        #pragma unroll
        for (int n = 0; n < 7; ++n) {
            float tempv = log1pf(expf(ntl[t*7+n] + 0.5413f));
            float v = (raw[lt][t*7+n] + db[t*7+n]) / tempv;
            dec[n] = 1.f / (1.f + expf(-v));
        }
        float g[12], gmax = -3e38f;
        #pragma unroll
        for (int tt = 0; tt < 12; ++tt) {
            g[tt] = raw[lt][84+tt] + gate_b[tt];
            gmax = fmaxf(gmax, g[tt]);
        }
        float gsum = 0.f;
        #pragma unroll
        for (int tt = 0; tt < 12; ++tt) gsum += expf(g[tt]-gmax);
        const float wgt = expf(g[t]-gmax) / gsum;
        const int tok = blockIdx.x*16 + lt;
        #pragma unroll
        for (int l = 0; l < 8; ++l) {
            float p = wgt; int node = 0;
            #pragma unroll
            for (int dpt = 0; dpt < 3; ++dpt) {
                int bit = (l >> (2-dpt)) & 1;
                float r = dec[node];
                p *= bit ? (1.f - r) : r;
                node = 2*node + 1 + bit;
            }
            coeffb[tok*96 + t*8 + l] = f2b(p);
        }
    }
}

// ---------------------------------------------------------------------------
// Kernel 2: leaf [3][96][1024] f32 -> leafT [3][1024][96] bf16
// ---------------------------------------------------------------------------
__global__ __launch_bounds__(256) void lt_kernel(
    const float* __restrict__ leaf, ushort* __restrict__ leafT)
{
    __shared__ float t[96][65];
    const int d0 = blockIdx.x * 64, h = blockIdx.y;
    const int tid = threadIdx.x;
    for (int i = tid; i < 96*16; i += 256) {
        int k = i >> 4, c4 = i & 15;
        *(float4*)&t[k][c4*4] = *(const float4*)&leaf[(size_t)(h*96 + k)*1024 + d0 + c4*4];
    }
    __syncthreads();
    const int d = tid >> 2, kq = (tid & 3) * 24;
    #pragma unroll
    for (int base = 0; base < 24; base += 8) {
        short8 o;
        #pragma unroll
        for (int j = 0; j < 8; ++j) o[j] = (short)f2b(t[kq+base+j][d]);
        *(short8*)&leafT[(size_t)(h*1024 + d0 + d)*96 + kq + base] = o;
    }
}

// ---------------------------------------------------------------------------
// Kernel 3: MFMA mix. C rows = d (leaf dim), cols = token.
// Q,K planes -> qkvb (8B vector stores); V plane -> vT directly.
// ---------------------------------------------------------------------------
__global__ __launch_bounds__(256) void mix_kernel(
    const ushort* __restrict__ coeffb,  // [4096][96] bf16
    const ushort* __restrict__ leafT,   // [3][1024][96] bf16
    ushort* __restrict__ qkvb,          // [2][4096][1024] bf16 (Q,K)
    ushort* __restrict__ vT)            // [64][64][1024] bf16
{
    const int bt = blockIdx.x;          // 64 token tiles of 64
    const int bd = blockIdx.y;          // 24 col tiles of 128 over 3072
    const int tid = threadIdx.x, w = tid >> 6, lane = tid & 63;
    const int lq = lane & 15, lg = lane >> 4;
    const int tok0 = bt*64 + w*16;
    const int c0 = bd*128;
    const int pl = c0 >> 10;            // 0=Q,1=K,2=V
    const int d0 = c0 & 1023;

    f32x4 acc[8];
    #pragma unroll
    for (int n = 0; n < 8; ++n) acc[n] = (f32x4){0.f,0.f,0.f,0.f};

    #pragma unroll
    for (int ks = 0; ks < 3; ++ks) {
        const int k0 = ks*32;
        short8 bfrag = *(const short8*)&coeffb[(tok0 + lq)*96 + k0 + lg*8];
        #pragma unroll
        for (int n = 0; n < 8; ++n) {
            short8 afrag = *(const short8*)&leafT[(size_t)(pl*1024 + d0 + n*16 + lq)*96 + k0 + lg*8];
            acc[n] = __builtin_amdgcn_mfma_f32_16x16x32_bf16(afrag, bfrag, acc[n], 0, 0, 0);
        }
    }

    const int tok = tok0 + lq;
    if (pl < 2) {
        #pragma unroll
        for (int n = 0; n < 8; ++n) {
            const int d = d0 + n*16 + lg*4;
            ushort4v u;
            u[0]=f2b(acc[n][0]); u[1]=f2b(acc[n][1]);
            u[2]=f2b(acc[n][2]); u[3]=f2b(acc[n][3]);
            *(ushort4v*)&qkvb[(size_t)pl*TOKS*1024 + (size_t)tok*1024 + d] = u;
        }
    } else {
        const int b = tok >> 10, seq = tok & 1023;
        #pragma unroll
        for (int n = 0; n < 8; ++n) {
            #pragma unroll
            for (int r = 0; r < 4; ++r) {
                const int d = d0 + n*16 + lg*4 + r;
                const int head = d >> 6, dh = d & 63;
                vT[((size_t)((b*16+head)*64 + dh))*1024 + seq] = f2b(acc[n][r]);
            }
        }
    }
}

// ---------------------------------------------------------------------------
// Kernel 4: out_w [1024][1024] f32 -> wT [n][k] bf16 (transpose + convert)
// ---------------------------------------------------------------------------
__global__ __launch_bounds__(256) void wtrans_kernel(
    const float* __restrict__ w, ushort* __restrict__ wT)
{
    __shared__ float t[64][65];
    const int n0 = blockIdx.x * 64, k0 = blockIdx.y * 64;
    const int tid = threadIdx.x;
    const int r = tid >> 2, c16 = (tid & 3) * 16;
    #pragma unroll
    for (int j = 0; j < 16; j += 4)
        *(float4*)&t[r][c16+j] = *(const float4*)&w[(size_t)(k0+r)*1024 + n0 + c16 + j];
    __syncthreads();
    short8 o0, o1;
    #pragma unroll
    for (int j = 0; j < 8; ++j) o0[j] = (short)f2b(t[c16+j][r]);
    #pragma unroll
    for (int j = 0; j < 8; ++j) o1[j] = (short)f2b(t[c16+8+j][r]);
    *(short8*)&wT[(size_t)(n0+r)*1024 + k0 + c16]     = o0;
    *(short8*)&wT[(size_t)(n0+r)*1024 + k0 + c16 + 8] = o1;
}

// ---------------------------------------------------------------------------
// Kernel 5: MFMA flash attention, single-wave blocks (64 thr, 16 q-rows).
// No thread barriers (single wave; DS ops are FIFO per wave). P^T staging
// uses a uint-typed LDS buffer accessed ONLY as uint (writes and reads) --
// consistent types keep compiler program order (the round-6 nan was uint
// writes / ushort reads: TBAA let the reads hoist above the writes once the
// round-3 __syncthreads was removed). wave_barrier() pins ordering at zero
// runtime cost. pTu stride 13 dwords: read bank = (kslot*13+lq/2)%32 -> all
// 32 banks, 2 lanes/bank (free).
// ---------------------------------------------------------------------------
__global__ __launch_bounds__(64) void attn_kernel(
    const ushort* __restrict__ qk,    // [2][4096][1024] bf16 (Q,K planes)
    const ushort* __restrict__ vT,    // [64][64][1024] bf16
    ushort* __restrict__ ctxb)        // [4096][1024] bf16
{
    const int id = blockIdx.x;
    const int bh = id & 63;
    const int qt = 63 - (id >> 6);    // q-tile (16 rows), descending work
    const int b = bh >> 4, h = bh & 15;
    const int lane = threadIdx.x;
    const int lq = lane & 15, lg = lane >> 4;
    __shared__ unsigned int pTu[64][13];   // P^T staging: [k][q-pair], uint-only

    const size_t plane = (size_t)TOKS*1024;
    const int tokq = b*1024 + qt*16 + lq;
    short8 aq[2];
    aq[0] = *(const short8*)&qk[(size_t)tokq*1024 + h*64 + lg*8];
    aq[1] = *(const short8*)&qk[(size_t)tokq*1024 + h*64 + 32 + lg*8];

    f32x4 o[4];
    #pragma unroll
    for (int n = 0; n < 4; ++n) o[n] = (f32x4){0.f,0.f,0.f,0.f};
    float m[4] = {-3e38f,-3e38f,-3e38f,-3e38f};
    float l[4] = {0.f,0.f,0.f,0.f};

    const ushort* Kp  = qk + plane;
    const ushort* vTp = vT + (size_t)bh*64*1024;
    const int nt = (qt >> 2) + 1;

    for (int t = 0; t < nt; ++t) {
        const int tk0 = b*1024 + t*64;
        f32x4 s[4];
        #pragma unroll
        for (int n = 0; n < 4; ++n) s[n] = (f32x4){0.f,0.f,0.f,0.f};
        #pragma unroll
        for (int kk = 0; kk < 2; ++kk)
            #pragma unroll
            for (int n = 0; n < 4; ++n) {
                short8 bk = *(const short8*)&Kp[(size_t)(tk0 + n*16 + lq)*1024 + h*64 + kk*32 + lg*8];
                s[n] = __builtin_amdgcn_mfma_f32_16x16x32_bf16(aq[kk], bk, s[n], 0, 0, 0);
            }

        // scale + causal mask: q = qt*16 + lg*4 + r, k = t*64 + n*16 + lq
        const bool diag = (t == nt-1);
        if (diag) {
            #pragma unroll
            for (int n = 0; n < 4; ++n)
                #pragma unroll
                for (int r = 0; r < 4; ++r) {
                    float v = s[n][r] * 0.125f;
                    if (t*64 + n*16 + lq > qt*16 + lg*4 + r) v = -1e9f;
                    s[n][r] = v;
                }
        } else {
            #pragma unroll
            for (int n = 0; n < 4; ++n)
                #pragma unroll
                for (int r = 0; r < 4; ++r) s[n][r] *= 0.125f;
        }

        #pragma unroll
        for (int r = 0; r < 4; ++r) {
            float rm = fmaxf(fmaxf(s[0][r], s[1][r]), fmaxf(s[2][r], s[3][r]));
            rm = fmaxf(rm, __shfl_xor(rm, 1));
            rm = fmaxf(rm, __shfl_xor(rm, 2));
            rm = fmaxf(rm, __shfl_xor(rm, 4));
            rm = fmaxf(rm, __shfl_xor(rm, 8));
            float mnew = fmaxf(m[r], rm);
            float corr = __expf(m[r] - mnew);
            float ps = 0.f;
            #pragma unroll
            for (int n = 0; n < 4; ++n) {
                float p = __expf(s[n][r] - mnew);
                s[n][r] = p; ps += p;
            }
            ps += __shfl_xor(ps, 1);
            ps += __shfl_xor(ps, 2);
            ps += __shfl_xor(ps, 4);
            ps += __shfl_xor(ps, 8);
            l[r] = l[r]*corr + ps;
            m[r] = mnew;
            o[0][r] *= corr; o[1][r] *= corr; o[2][r] *= corr; o[3][r] *= corr;
        }

        // P (bf16-packed) -> pTu[k][q/2] (uint writes, same-wave FIFO)
        #pragma unroll
        for (int n = 0; n < 4; ++n) {
            unsigned int lo = (unsigned int)f2b(s[n][0]) | ((unsigned int)f2b(s[n][1]) << 16);
            unsigned int hi = (unsigned int)f2b(s[n][2]) | ((unsigned int)f2b(s[n][3]) << 16);
            pTu[n*16 + lq][lg*2]     = lo;   // q cols lg*4, lg*4+1
            pTu[n*16 + lq][lg*2 + 1] = hi;   // q cols lg*4+2, lg*4+3
        }
        __builtin_amdgcn_wave_barrier();

        short8 pa[2];
        #pragma unroll
        for (int kk = 0; kk < 2; ++kk)
            #pragma unroll
            for (int j = 0; j < 8; ++j) {
                unsigned int u = pTu[kk*32 + lg*8 + j][lq >> 1];
                pa[kk][j] = (short)(ushort)(u >> ((lq & 1) * 16));
            }
        __builtin_amdgcn_wave_barrier();

        #pragma unroll
        for (int kk = 0; kk < 2; ++kk)
            #pragma unroll
            for (int n = 0; n < 4; ++n) {
                short8 bv = *(const short8*)&vTp[(size_t)(n*16 + lq)*1024 + t*64 + kk*32 + lg*8];
                o[n] = __builtin_amdgcn_mfma_f32_16x16x32_bf16(pa[kk], bv, o[n], 0, 0, 0);
            }
    }

    #pragma unroll
    for (int r = 0; r < 4; ++r) {
        float inv = 1.f / l[r];
        int row = b*1024 + qt*16 + lg*4 + r;
        #pragma unroll
        for (int n = 0; n < 4; ++n)
            ctxb[(size_t)row*1024 + h*64 + n*16 + lq] = f2b(o[n][r] * inv);
    }
}

// ---------------------------------------------------------------------------
// Kernel 6: out = ctx(bf16) @ wT(bf16)^T + bias, MFMA. 128x128 block tile.
// ---------------------------------------------------------------------------
__global__ __launch_bounds__(256) void proj_kernel(
    const ushort* __restrict__ A,     // ctx bf16 [4096][1024]
    const ushort* __restrict__ Bt,    // wT bf16 [1024(n)][1024(k)]
    const float* __restrict__ bias,   // [1024]
    float* __restrict__ out)          // [4096][1024]
{
    const int bn = blockIdx.x, bm = blockIdx.y;
    const int tid = threadIdx.x, w = tid >> 6, lane = tid & 63;
    const int wm = w >> 1, wn = w & 1;
    const int lq = lane & 15, lg = lane >> 4;
    const int row0 = bm*128 + wm*64;
    const int col0 = bn*128 + wn*64;

    f32x4 acc[4][4];
    #pragma unroll
    for (int i = 0; i < 4; ++i)
        #pragma unroll
        for (int j = 0; j < 4; ++j) acc[i][j] = (f32x4){0.f,0.f,0.f,0.f};

    for (int k0 = 0; k0 < 1024; k0 += 32) {
        short8 a[4], bfr[4];
        #pragma unroll
        for (int i = 0; i < 4; ++i)
            a[i] = *(const short8*)&A[(size_t)(row0 + i*16 + lq)*1024 + k0 + lg*8];
        #pragma unroll
        for (int j = 0; j < 4; ++j)
            bfr[j] = *(const short8*)&Bt[(size_t)(col0 + j*16 + lq)*1024 + k0 + lg*8];
        #pragma unroll
        for (int i = 0; i < 4; ++i)
            #pragma unroll
            for (int j = 0; j < 4; ++j)
                acc[i][j] = __builtin_amdgcn_mfma_f32_16x16x32_bf16(a[i], bfr[j], acc[i][j], 0, 0, 0);
    }

    #pragma unroll
    for (int i = 0; i < 4; ++i)
        #pragma unroll
        for (int j = 0; j < 4; ++j) {
            int col = col0 + j*16 + lq;
            float bb = bias[col];
            #pragma unroll
            for (int r = 0; r < 4; ++r)
                out[(size_t)(row0 + i*16 + lg*4 + r)*1024 + col] = acc[i][j][r] + bb;
        }
}

// ---------------------------------------------------------------------------
extern "C" void kernel_launch(void* const* d_in, const int* in_sizes, int n_in,
                              void* d_out, int out_size, void* d_ws, size_t ws_size,
                              hipStream_t stream) {
    (void)in_sizes; (void)n_in; (void)out_size; (void)ws_size;
    const float* x      = (const float*)d_in[0];
    const float* dw     = (const float*)d_in[1];
    const float* db     = (const float*)d_in[2];
    const float* ntl    = (const float*)d_in[3];
    const float* gate_w = (const float*)d_in[4];
    const float* gate_b = (const float*)d_in[5];
    const float* leaf   = (const float*)d_in[6];
    const float* out_w  = (const float*)d_in[7];
    const float* out_b  = (const float*)d_in[8];
    float* out = (float*)d_out;

    // ws layout (bytes): coeffb@0 (0.75MB) | qkvb@2MB (16MB, Q+K) | vT@20MB (8MB)
    //                    ctxb@30MB (8MB) | wT@40MB (2MB) | leafT@44MB (0.6MB)
    ushort* coeffb = (ushort*)d_ws;
    ushort* qkvb   = (ushort*)((char*)d_ws + ((size_t)2u  << 20));
    ushort* vT     = (ushort*)((char*)d_ws + ((size_t)20u << 20));
    ushort* ctxb   = (ushort*)((char*)d_ws + ((size_t)30u << 20));
    ushort* wT     = (ushort*)((char*)d_ws + ((size_t)40u << 20));
    ushort* leafT  = (ushort*)((char*)d_ws + ((size_t)44u << 20));

    hipLaunchKernelGGL(routing_kernel, dim3(256),     dim3(256), 0, stream,
                       x, dw, db, ntl, gate_w, gate_b, coeffb);
    hipLaunchKernelGGL(lt_kernel,      dim3(16, 3),   dim3(256), 0, stream,
                       leaf, leafT);
    hipLaunchKernelGGL(wtrans_kernel,  dim3(16, 16),  dim3(256), 0, stream,
                       out_w, wT);
    hipLaunchKernelGGL(mix_kernel,     dim3(64, 24),  dim3(256), 0, stream,
                       coeffb, leafT, qkvb, vT);
    hipLaunchKernelGGL(attn_kernel,    dim3(4096),    dim3(64),  0, stream,
                       qkvb, vT, ctxb);
    hipLaunchKernelGGL(proj_kernel,    dim3(8, 32),   dim3(256), 0, stream,
                       ctxb, wT, out_b, out);
}

// Round 10
// 275.733 us; speedup vs baseline: 2.6420x; 1.0721x over previous
//
#include <hip/hip_runtime.h>
#include <hip/hip_bf16.h>
#include <math.h>

#define TOKS 4096

typedef __attribute__((ext_vector_type(4))) float    f32x4;
typedef __attribute__((ext_vector_type(8))) short    short8;
typedef __attribute__((ext_vector_type(4))) unsigned short ushort4v;
typedef unsigned short ushort;

__device__ __forceinline__ ushort f2b(float f) {   // f32 -> bf16 bits, RNE
    unsigned int b = __float_as_uint(f);
    b += 0x7fff + ((b >> 16) & 1);
    return (ushort)(b >> 16);
}

// ---------------------------------------------------------------------------
// Kernel 0: pack routing weights: Wb[96][1024] bf16 = [dw(84 rows) ; gate_w^T]
// ---------------------------------------------------------------------------
__global__ __launch_bounds__(256) void wb_kernel(
    const float* __restrict__ dw,      // [84][1024]
    const float* __restrict__ gate_w,  // [1024][12]
    ushort* __restrict__ Wb)           // [96][1024] bf16
{
    const int i = blockIdx.x * 256 + threadIdx.x;   // 48 blocks: 96*1024/8
    const int row = i >> 7, k0 = (i & 127) * 8;
    short8 o;
    if (row < 84) {
        float4 a0 = *(const float4*)&dw[(size_t)row*1024 + k0];
        float4 a1 = *(const float4*)&dw[(size_t)row*1024 + k0 + 4];
        o[0]=(short)f2b(a0.x); o[1]=(short)f2b(a0.y); o[2]=(short)f2b(a0.z); o[3]=(short)f2b(a0.w);
        o[4]=(short)f2b(a1.x); o[5]=(short)f2b(a1.y); o[6]=(short)f2b(a1.z); o[7]=(short)f2b(a1.w);
    } else {
        const int t = row - 84;
        #pragma unroll
        for (int j = 0; j < 8; ++j) o[j] = (short)f2b(gate_w[(size_t)(k0+j)*12 + t]);
    }
    *(short8*)&Wb[(size_t)row*1024 + k0] = o;
}

// ---------------------------------------------------------------------------
// Kernel 1: fused routing: logits = x @ Wb^T via MFMA (1 wave / 16 tokens),
// then in-block sigmoid/leaf-prob/gate-softmax postprocess -> coeffb bf16.
// ---------------------------------------------------------------------------
__global__ __launch_bounds__(64) void route2_kernel(
    const float* __restrict__ x,        // [4096][1024]
    const ushort* __restrict__ Wb,      // [96][1024] bf16
    const float* __restrict__ db,       // [84]
    const float* __restrict__ ntl,      // [84]
    const float* __restrict__ gate_b,   // [12]
    ushort* __restrict__ coeffb)        // [4096][96] bf16
{
    const int tok0 = blockIdx.x * 16;
    const int lane = threadIdx.x;
    const int lq = lane & 15, lg = lane >> 4;
    __shared__ float lgt[16][97];       // logits [token][96], pad 97

    f32x4 acc[6];
    #pragma unroll
    for (int n = 0; n < 6; ++n) acc[n] = (f32x4){0.f,0.f,0.f,0.f};

    for (int k0 = 0; k0 < 1024; k0 += 32) {
        float4 a0 = *(const float4*)&x[(size_t)(tok0 + lq)*1024 + k0 + lg*8];
        float4 a1 = *(const float4*)&x[(size_t)(tok0 + lq)*1024 + k0 + lg*8 + 4];
        short8 af;
        af[0]=(short)f2b(a0.x); af[1]=(short)f2b(a0.y); af[2]=(short)f2b(a0.z); af[3]=(short)f2b(a0.w);
        af[4]=(short)f2b(a1.x); af[5]=(short)f2b(a1.y); af[6]=(short)f2b(a1.z); af[7]=(short)f2b(a1.w);
        #pragma unroll
        for (int n = 0; n < 6; ++n) {
            short8 bf_ = *(const short8*)&Wb[(size_t)(n*16 + lq)*1024 + k0 + lg*8];
            acc[n] = __builtin_amdgcn_mfma_f32_16x16x32_bf16(af, bf_, acc[n], 0, 0, 0);
        }
    }

    // C frag -> LDS: token = lg*4+r, col = n*16+lq
    #pragma unroll
    for (int n = 0; n < 6; ++n)
        #pragma unroll
        for (int r = 0; r < 4; ++r)
            lgt[lg*4 + r][n*16 + lq] = acc[n][r];
    __builtin_amdgcn_wave_barrier();

    // postprocess: 64 threads x 3 (tok,tree) jobs
    const int tok = lane >> 2;
    #pragma unroll
    for (int tj = 0; tj < 3; ++tj) {
        const int t = (lane & 3)*3 + tj;
        float dec[7];
        #pragma unroll
        for (int n = 0; n < 7; ++n) {
            float tempv = log1pf(expf(ntl[t*7+n] + 0.5413f));
            float v = (lgt[tok][t*7+n] + db[t*7+n]) / tempv;
            dec[n] = 1.f / (1.f + expf(-v));
        }
        float g[12], gmax = -3e38f;
        #pragma unroll
        for (int tt = 0; tt < 12; ++tt) {
            g[tt] = lgt[tok][84+tt] + gate_b[tt];
            gmax = fmaxf(gmax, g[tt]);
        }
        float gsum = 0.f;
        #pragma unroll
        for (int tt = 0; tt < 12; ++tt) gsum += expf(g[tt]-gmax);
        const float wgt = expf(g[t]-gmax) / gsum;
        short8 co;
        #pragma unroll
        for (int l = 0; l < 8; ++l) {
            float p = wgt; int node = 0;
            #pragma unroll
            for (int dpt = 0; dpt < 3; ++dpt) {
                int bit = (l >> (2-dpt)) & 1;
                float r = dec[node];
                p *= bit ? (1.f - r) : r;
                node = 2*node + 1 + bit;
            }
            co[l] = (short)f2b(p);
        }
        *(short8*)&coeffb[(size_t)(tok0 + tok)*96 + t*8] = co;
    }
}

// ---------------------------------------------------------------------------
// Kernel 2: leaf [3][96][1024] f32 -> leafT [3][1024][96] bf16
// ---------------------------------------------------------------------------
__global__ __launch_bounds__(256) void lt_kernel(
    const float* __restrict__ leaf, ushort* __restrict__ leafT)
{
    __shared__ float t[96][65];
    const int d0 = blockIdx.x * 64, h = blockIdx.y;
    const int tid = threadIdx.x;
    for (int i = tid; i < 96*16; i += 256) {
        int k = i >> 4, c4 = i & 15;
        *(float4*)&t[k][c4*4] = *(const float4*)&leaf[(size_t)(h*96 + k)*1024 + d0 + c4*4];
    }
    __syncthreads();
    const int d = tid >> 2, kq = (tid & 3) * 24;
    #pragma unroll
    for (int base = 0; base < 24; base += 8) {
        short8 o;
        #pragma unroll
        for (int j = 0; j < 8; ++j) o[j] = (short)f2b(t[kq+base+j][d]);
        *(short8*)&leafT[(size_t)(h*1024 + d0 + d)*96 + kq + base] = o;
    }
}

// ---------------------------------------------------------------------------
// Kernel 3: MFMA mix. C rows = d (leaf dim), cols = token.
// Q,K planes -> qkvb (8B vector stores); V plane -> vT directly.
// ---------------------------------------------------------------------------
__global__ __launch_bounds__(256) void mix_kernel(
    const ushort* __restrict__ coeffb,  // [4096][96] bf16
    const ushort* __restrict__ leafT,   // [3][1024][96] bf16
    ushort* __restrict__ qkvb,          // [2][4096][1024] bf16 (Q,K)
    ushort* __restrict__ vT)            // [64][64][1024] bf16
{
    const int bt = blockIdx.x;          // 64 token tiles of 64
    const int bd = blockIdx.y;          // 24 col tiles of 128 over 3072
    const int tid = threadIdx.x, w = tid >> 6, lane = tid & 63;
    const int lq = lane & 15, lg = lane >> 4;
    const int tok0 = bt*64 + w*16;
    const int c0 = bd*128;
    const int pl = c0 >> 10;            // 0=Q,1=K,2=V
    const int d0 = c0 & 1023;

    f32x4 acc[8];
    #pragma unroll
    for (int n = 0; n < 8; ++n) acc[n] = (f32x4){0.f,0.f,0.f,0.f};

    #pragma unroll
    for (int ks = 0; ks < 3; ++ks) {
        const int k0 = ks*32;
        short8 bfrag = *(const short8*)&coeffb[(tok0 + lq)*96 + k0 + lg*8];
        #pragma unroll
        for (int n = 0; n < 8; ++n) {
            short8 afrag = *(const short8*)&leafT[(size_t)(pl*1024 + d0 + n*16 + lq)*96 + k0 + lg*8];
            acc[n] = __builtin_amdgcn_mfma_f32_16x16x32_bf16(afrag, bfrag, acc[n], 0, 0, 0);
        }
    }

    const int tok = tok0 + lq;
    if (pl < 2) {
        #pragma unroll
        for (int n = 0; n < 8; ++n) {
            const int d = d0 + n*16 + lg*4;
            ushort4v u;
            u[0]=f2b(acc[n][0]); u[1]=f2b(acc[n][1]);
            u[2]=f2b(acc[n][2]); u[3]=f2b(acc[n][3]);
            *(ushort4v*)&qkvb[(size_t)pl*TOKS*1024 + (size_t)tok*1024 + d] = u;
        }
    } else {
        const int b = tok >> 10, seq = tok & 1023;
        #pragma unroll
        for (int n = 0; n < 8; ++n) {
            #pragma unroll
            for (int r = 0; r < 4; ++r) {
                const int d = d0 + n*16 + lg*4 + r;
                const int head = d >> 6, dh = d & 63;
                vT[((size_t)((b*16+head)*64 + dh))*1024 + seq] = f2b(acc[n][r]);
            }
        }
    }
}

// ---------------------------------------------------------------------------
// Kernel 4: out_w [1024][1024] f32 -> wT [n][k] bf16 (transpose + convert)
// ---------------------------------------------------------------------------
__global__ __launch_bounds__(256) void wtrans_kernel(
    const float* __restrict__ w, ushort* __restrict__ wT)
{
    __shared__ float t[64][65];
    const int n0 = blockIdx.x * 64, k0 = blockIdx.y * 64;
    const int tid = threadIdx.x;
    const int r = tid >> 2, c16 = (tid & 3) * 16;
    #pragma unroll
    for (int j = 0; j < 16; j += 4)
        *(float4*)&t[r][c16+j] = *(const float4*)&w[(size_t)(k0+r)*1024 + n0 + c16 + j];
    __syncthreads();
    short8 o0, o1;
    #pragma unroll
    for (int j = 0; j < 8; ++j) o0[j] = (short)f2b(t[c16+j][r]);
    #pragma unroll
    for (int j = 0; j < 8; ++j) o1[j] = (short)f2b(t[c16+8+j][r]);
    *(short8*)&wT[(size_t)(n0+r)*1024 + k0 + c16]     = o0;
    *(short8*)&wT[(size_t)(n0+r)*1024 + k0 + c16 + 8] = o1;
}

// ---------------------------------------------------------------------------
// Kernel 5: MFMA flash attention, single-wave blocks (64 thr, 16 q-rows).
// uint-typed pT staging (TBAA-safe), no barriers, LPT dispatch order.
// ---------------------------------------------------------------------------
__global__ __launch_bounds__(64) void attn_kernel(
    const ushort* __restrict__ qk,    // [2][4096][1024] bf16 (Q,K planes)
    const ushort* __restrict__ vT,    // [64][64][1024] bf16
    ushort* __restrict__ ctxb)        // [4096][1024] bf16
{
    const int id = blockIdx.x;
    const int bh = id & 63;
    const int qt = 63 - (id >> 6);    // q-tile (16 rows), descending work
    const int b = bh >> 4, h = bh & 15;
    const int lane = threadIdx.x;
    const int lq = lane & 15, lg = lane >> 4;
    __shared__ unsigned int pTu[64][13];   // P^T staging: [k][q-pair], uint-only

    const size_t plane = (size_t)TOKS*1024;
    const int tokq = b*1024 + qt*16 + lq;
    short8 aq[2];
    aq[0] = *(const short8*)&qk[(size_t)tokq*1024 + h*64 + lg*8];
    aq[1] = *(const short8*)&qk[(size_t)tokq*1024 + h*64 + 32 + lg*8];

    f32x4 o[4];
    #pragma unroll
    for (int n = 0; n < 4; ++n) o[n] = (f32x4){0.f,0.f,0.f,0.f};
    float m[4] = {-3e38f,-3e38f,-3e38f,-3e38f};
    float l[4] = {0.f,0.f,0.f,0.f};

    const ushort* Kp  = qk + plane;
    const ushort* vTp = vT + (size_t)bh*64*1024;
    const int nt = (qt >> 2) + 1;

    for (int t = 0; t < nt; ++t) {
        const int tk0 = b*1024 + t*64;
        f32x4 s[4];
        #pragma unroll
        for (int n = 0; n < 4; ++n) s[n] = (f32x4){0.f,0.f,0.f,0.f};
        #pragma unroll
        for (int kk = 0; kk < 2; ++kk)
            #pragma unroll
            for (int n = 0; n < 4; ++n) {
                short8 bk = *(const short8*)&Kp[(size_t)(tk0 + n*16 + lq)*1024 + h*64 + kk*32 + lg*8];
                s[n] = __builtin_amdgcn_mfma_f32_16x16x32_bf16(aq[kk], bk, s[n], 0, 0, 0);
            }

        const bool diag = (t == nt-1);
        if (diag) {
            #pragma unroll
            for (int n = 0; n < 4; ++n)
                #pragma unroll
                for (int r = 0; r < 4; ++r) {
                    float v = s[n][r] * 0.125f;
                    if (t*64 + n*16 + lq > qt*16 + lg*4 + r) v = -1e9f;
                    s[n][r] = v;
                }
        } else {
            #pragma unroll
            for (int n = 0; n < 4; ++n)
                #pragma unroll
                for (int r = 0; r < 4; ++r) s[n][r] *= 0.125f;
        }

        #pragma unroll
        for (int r = 0; r < 4; ++r) {
            float rm = fmaxf(fmaxf(s[0][r], s[1][r]), fmaxf(s[2][r], s[3][r]));
            rm = fmaxf(rm, __shfl_xor(rm, 1));
            rm = fmaxf(rm, __shfl_xor(rm, 2));
            rm = fmaxf(rm, __shfl_xor(rm, 4));
            rm = fmaxf(rm, __shfl_xor(rm, 8));
            float mnew = fmaxf(m[r], rm);
            float corr = __expf(m[r] - mnew);
            float ps = 0.f;
            #pragma unroll
            for (int n = 0; n < 4; ++n) {
                float p = __expf(s[n][r] - mnew);
                s[n][r] = p; ps += p;
            }
            ps += __shfl_xor(ps, 1);
            ps += __shfl_xor(ps, 2);
            ps += __shfl_xor(ps, 4);
            ps += __shfl_xor(ps, 8);
            l[r] = l[r]*corr + ps;
            m[r] = mnew;
            o[0][r] *= corr; o[1][r] *= corr; o[2][r] *= corr; o[3][r] *= corr;
        }

        // P (bf16-packed) -> pTu[k][q/2] (uint writes, same-wave FIFO)
        #pragma unroll
        for (int n = 0; n < 4; ++n) {
            unsigned int lo = (unsigned int)f2b(s[n][0]) | ((unsigned int)f2b(s[n][1]) << 16);
            unsigned int hi = (unsigned int)f2b(s[n][2]) | ((unsigned int)f2b(s[n][3]) << 16);
            pTu[n*16 + lq][lg*2]     = lo;
            pTu[n*16 + lq][lg*2 + 1] = hi;
        }
        __builtin_amdgcn_wave_barrier();

        short8 pa[2];
        #pragma unroll
        for (int kk = 0; kk < 2; ++kk)
            #pragma unroll
            for (int j = 0; j < 8; ++j) {
                unsigned int u = pTu[kk*32 + lg*8 + j][lq >> 1];
                pa[kk][j] = (short)(ushort)(u >> ((lq & 1) * 16));
            }
        __builtin_amdgcn_wave_barrier();

        #pragma unroll
        for (int kk = 0; kk < 2; ++kk)
            #pragma unroll
            for (int n = 0; n < 4; ++n) {
                short8 bv = *(const short8*)&vTp[(size_t)(n*16 + lq)*1024 + t*64 + kk*32 + lg*8];
                o[n] = __builtin_amdgcn_mfma_f32_16x16x32_bf16(pa[kk], bv, o[n], 0, 0, 0);
            }
    }

    #pragma unroll
    for (int r = 0; r < 4; ++r) {
        float inv = 1.f / l[r];
        int row = b*1024 + qt*16 + lg*4 + r;
        #pragma unroll
        for (int n = 0; n < 4; ++n)
            ctxb[(size_t)row*1024 + h*64 + n*16 + lq] = f2b(o[n][r] * inv);
    }
}

// ---------------------------------------------------------------------------
// Kernel 6: out = ctx(bf16) @ wT(bf16)^T + bias, MFMA. 128x128 block tile.
// ---------------------------------------------------------------------------
__global__ __launch_bounds__(256) void proj_kernel(
    const ushort* __restrict__ A,     // ctx bf16 [4096][1024]
    const ushort* __restrict__ Bt,    // wT bf16 [1024(n)][1024(k)]
    const float* __restrict__ bias,   // [1024]
    float* __restrict__ out)          // [4096][1024]
{
    const int bn = blockIdx.x, bm = blockIdx.y;
    const int tid = threadIdx.x, w = tid >> 6, lane = tid & 63;
    const int wm = w >> 1, wn = w & 1;
    const int lq = lane & 15, lg = lane >> 4;
    const int row0 = bm*128 + wm*64;
    const int col0 = bn*128 + wn*64;

    f32x4 acc[4][4];
    #pragma unroll
    for (int i = 0; i < 4; ++i)
        #pragma unroll
        for (int j = 0; j < 4; ++j) acc[i][j] = (f32x4){0.f,0.f,0.f,0.f};

    for (int k0 = 0; k0 < 1024; k0 += 32) {
        short8 a[4], bfr[4];
        #pragma unroll
        for (int i = 0; i < 4; ++i)
            a[i] = *(const short8*)&A[(size_t)(row0 + i*16 + lq)*1024 + k0 + lg*8];
        #pragma unroll
        for (int j = 0; j < 4; ++j)
            bfr[j] = *(const short8*)&Bt[(size_t)(col0 + j*16 + lq)*1024 + k0 + lg*8];
        #pragma unroll
        for (int i = 0; i < 4; ++i)
            #pragma unroll
            for (int j = 0; j < 4; ++j)
                acc[i][j] = __builtin_amdgcn_mfma_f32_16x16x32_bf16(a[i], bfr[j], acc[i][j], 0, 0, 0);
    }

    #pragma unroll
    for (int i = 0; i < 4; ++i)
        #pragma unroll
        for (int j = 0; j < 4; ++j) {
            int col = col0 + j*16 + lq;
            float bb = bias[col];
            #pragma unroll
            for (int r = 0; r < 4; ++r)
                out[(size_t)(row0 + i*16 + lg*4 + r)*1024 + col] = acc[i][j][r] + bb;
        }
}

// ---------------------------------------------------------------------------
extern "C" void kernel_launch(void* const* d_in, const int* in_sizes, int n_in,
                              void* d_out, int out_size, void* d_ws, size_t ws_size,
                              hipStream_t stream) {
    (void)in_sizes; (void)n_in; (void)out_size; (void)ws_size;
    const float* x      = (const float*)d_in[0];
    const float* dw     = (const float*)d_in[1];
    const float* db     = (const float*)d_in[2];
    const float* ntl    = (const float*)d_in[3];
    const float* gate_w = (const float*)d_in[4];
    const float* gate_b = (const float*)d_in[5];
    const float* leaf   = (const float*)d_in[6];
    const float* out_w  = (const float*)d_in[7];
    const float* out_b  = (const float*)d_in[8];
    float* out = (float*)d_out;

    // ws layout (bytes): coeffb@0 (0.75MB) | Wb@1MB (0.2MB) | qkvb@2MB (16MB)
    //                    vT@20MB (8MB) | ctxb@30MB (8MB) | wT@40MB (2MB) | leafT@44MB (0.6MB)
    ushort* coeffb = (ushort*)d_ws;
    ushort* Wb     = (ushort*)((char*)d_ws + ((size_t)1u  << 20));
    ushort* qkvb   = (ushort*)((char*)d_ws + ((size_t)2u  << 20));
    ushort* vT     = (ushort*)((char*)d_ws + ((size_t)20u << 20));
    ushort* ctxb   = (ushort*)((char*)d_ws + ((size_t)30u << 20));
    ushort* wT     = (ushort*)((char*)d_ws + ((size_t)40u << 20));
    ushort* leafT  = (ushort*)((char*)d_ws + ((size_t)44u << 20));

    hipLaunchKernelGGL(wb_kernel,      dim3(48),      dim3(256), 0, stream,
                       dw, gate_w, Wb);
    hipLaunchKernelGGL(lt_kernel,      dim3(16, 3),   dim3(256), 0, stream,
                       leaf, leafT);
    hipLaunchKernelGGL(wtrans_kernel,  dim3(16, 16),  dim3(256), 0, stream,
                       out_w, wT);
    hipLaunchKernelGGL(route2_kernel,  dim3(256),     dim3(64),  0, stream,
                       x, Wb, db, ntl, gate_b, coeffb);
    hipLaunchKernelGGL(mix_kernel,     dim3(64, 24),  dim3(256), 0, stream,
                       coeffb, leafT, qkvb, vT);
    hipLaunchKernelGGL(attn_kernel,    dim3(4096),    dim3(64),  0, stream,
                       qkvb, vT, ctxb);
    hipLaunchKernelGGL(proj_kernel,    dim3(8, 32),   dim3(256), 0, stream,
                       ctxb, wT, out_b, out);
}